// Round 3
// baseline (405.803 us; speedup 1.0000x reference)
//
#include <hip/hip_runtime.h>

// CTC batch cost forward, B=256, T=256, C=1000, L=64, S=129, blank=999.
// ROUND 3: two-phase split.
//   Phase 1: gather + log — one wave per (b,t), 65536 waves (8/SIMD) give the
//            MLP needed to saturate HBM on the scattered 65-column gather.
//            Writes compact lp table [B*T][66] = 17.3 MB into d_ws.
//   Phase 2: round-2's validated single-wave recursion (zero barriers), now
//            fed by dense coalesced loads from the compact table (LLC-hot),
//            8-deep register prefetch ring.

#define T_    256
#define C_    1000
#define L_    64
#define BLANK 999       // C-1
#define NEGF  (-1e30f)
#define EPSF  (1e-7f)
#define RS    66        // lp row stride (floats): [blank, lab0..lab63, pad]
#define PD    8         // phase-2 prefetch depth (t-steps)

// ---------------- Phase 1: gather + log ----------------
__global__ __launch_bounds__(256)
void ctc_gather_kernel(const int* __restrict__ y_true,
                       const float* __restrict__ y_pred,
                       float* __restrict__ lp) {
    const int wave = threadIdx.x >> 6;            // 0..3
    const int lane = threadIdx.x & 63;
    const int pair = blockIdx.x * 4 + wave;       // b*256 + t, 0..65535
    const int b = pair >> 8;
    const int t = pair & 255;

    const int lab = y_true[b * L_ + lane];        // coalesced, L2-hot
    const float* __restrict__ row = y_pred + (size_t)pair * C_;  // == (b*T+t)*C
    float* __restrict__ orow = lp + (size_t)pair * RS;

    // Scattered gather: 64 label columns + blank (lane 0).
    float v = row[lab];
    orow[1 + lane] = __logf(v + EPSF);
    if (lane == 0) {
        orow[0] = __logf(row[BLANK] + EPSF);
    }
}

// ---------------- Phase 2: per-row recursion ----------------
__global__ __launch_bounds__(64)
void ctc_scan_kernel(const int* __restrict__ y_true,
                     const float* __restrict__ lp,
                     float* __restrict__ out) {
    const int b    = blockIdx.x;
    const int lane = threadIdx.x;                 // 0..63

    const float* __restrict__ lrow = lp + (size_t)b * T_ * RS;

    // Skip-transition permission for odd state 2*lane+1.
    const int lab   = y_true[b * L_ + lane];
    const int labm1 = __shfl_up(lab, 1, 64);
    const bool allow = (lane > 0) && (lab != labm1);

    // t = 0 init: alpha[0]=lp_blank(0), alpha[1]=lp(lab0, 0), rest NEG.
    float aE = (lane == 0) ? lrow[0] : NEGF;      // alpha[2i]
    float aO = (lane == 0) ? lrow[1] : NEGF;      // alpha[2i+1]
    float aL = NEGF;                              // alpha[128] (lane-63 local)

    // Prefetch ring for t = 1..PD.
    float pB[PD], pL[PD];
    #pragma unroll
    for (int k = 0; k < PD; ++k) {
        int t = 1 + k; if (t > T_ - 1) t = T_ - 1;
        pB[k] = lrow[t * RS];                     // broadcast (same addr)
        pL[k] = lrow[t * RS + 1 + lane];          // coalesced 256B
    }

    for (int tb = 1; tb < T_; tb += PD) {
        #pragma unroll
        for (int j = 0; j < PD; ++j) {
            const int t = tb + j;
            if (t >= T_) break;                   // uniform across wave

            int tn = t + PD; if (tn > T_ - 1) tn = T_ - 1;
            float nB = lrow[tn * RS];
            float nL = lrow[tn * RS + 1 + lane];

            const float lpB = pB[j];
            const float lpL = pL[j];

            // Cross-lane: alpha_old[2i-1] from lane i-1.
            float upO = __shfl_up(aO, 1, 64);
            if (lane == 0) upO = NEGF;

            // s = 2i (blank): from {2i, 2i-1}.
            float mE = fmaxf(aE, upO);
            float nE = mE + __logf(__expf(aE - mE) + __expf(upO - mE)) + lpB;

            // s = 2i+1 (label): from {2i+1, 2i, 2i-1 if allowed}.
            float sk = allow ? upO : NEGF;
            float mO = fmaxf(fmaxf(aO, aE), sk);
            float nO = mO + __logf(__expf(aO - mO) + __expf(aE - mO) +
                                   __expf(sk - mO)) + lpL;

            // s = 128 (blank): from {128, 127}.
            float mL = fmaxf(aL, aO);
            float nL2 = mL + __logf(__expf(aL - mL) + __expf(aO - mL)) + lpB;

            aE = nE; aO = nO; aL = nL2;
            pB[j] = nB; pL[j] = nL;
        }
    }

    // loss = -logaddexp(alpha[128]=aL, alpha[127]=aO) at lane 63.
    if (lane == 63) {
        float m = fmaxf(aL, aO);
        out[b] = -(m + __logf(__expf(aL - m) + __expf(aO - m)));
    }
}

extern "C" void kernel_launch(void* const* d_in, const int* in_sizes, int n_in,
                              void* d_out, int out_size, void* d_ws, size_t ws_size,
                              hipStream_t stream) {
    const int*   y_true = (const int*)d_in[0];
    const float* y_pred = (const float*)d_in[1];
    float*       out    = (float*)d_out;
    float*       lp     = (float*)d_ws;          // 256*256*66*4 = 17.3 MB
    (void)in_sizes; (void)n_in; (void)ws_size; (void)out_size;

    ctc_gather_kernel<<<dim3((256 * 256) / 4), dim3(256), 0, stream>>>(y_true, y_pred, lp);
    ctc_scan_kernel<<<dim3(256), dim3(64), 0, stream>>>(y_true, lp, out);
}

// Round 4
// 401.168 us; speedup vs baseline: 1.0116x; 1.0116x over previous
//
#include <hip/hip_runtime.h>

// CTC batch cost forward, B=256, T=256, C=1000, L=64, S=129, blank=999.
// ROUND 4: two-phase; phase-2 scan reads ONLY LDS in steady state.
//   Phase 1: gather + log, one wave per (b,t) (65536 waves -> HBM-saturating
//            MLP); writes compact lp table [B*T][RS=68] fp32 into d_ws.
//   Phase 2: one wave per row. The 69.6 KB lp strip is staged into LDS in
//            4 chunks of 17.4 KB via a register double-buffer (load c+1 ->
//            scan c from LDS -> ds_write c+1 -> load c+2). Single wave =>
//            no barriers; compiler's in-order vmcnt/lgkmcnt hides chunk
//            load latency under the ~7k-cycle chunk scan. The 255-step
//            recursion chain sees only ds_read (2-row ring prefetch).

#define T_    256
#define C_    1000
#define L_    64
#define BLANK 999       // C-1
#define NEGF  (-1e30f)
#define EPSF  (1e-7f)
#define RS    68        // lp row stride (floats): 272 B = 17 float4
#define CK    64        // t-steps per LDS chunk
#define NV    17        // float4 per lane per chunk: 64*68/(64*4)

// ---------------- Phase 1: gather + log ----------------
__global__ __launch_bounds__(256)
void ctc_gather_kernel(const int* __restrict__ y_true,
                       const float* __restrict__ y_pred,
                       float* __restrict__ lp) {
    const int wave = threadIdx.x >> 6;            // 0..3
    const int lane = threadIdx.x & 63;
    const int pair = blockIdx.x * 4 + wave;       // b*256 + t
    const int b = pair >> 8;

    const int lab = y_true[b * L_ + lane];        // coalesced, cache-hot
    const float* __restrict__ row = y_pred + (size_t)pair * C_;
    float* __restrict__ orow = lp + (size_t)pair * RS;

    float v = row[lab];                           // scattered gather
    orow[1 + lane] = __logf(v + EPSF);
    if (lane == 0) {
        orow[0] = __logf(row[BLANK] + EPSF);
    }
}

// ---------------- Phase 2: per-row recursion ----------------
__global__ __launch_bounds__(64)
void ctc_scan_kernel(const int* __restrict__ y_true,
                     const float* __restrict__ lp,
                     float* __restrict__ out) {
    __shared__ float sbuf[2][CK * RS];            // 2 x 17408 B = 34.8 KB

    const int b    = blockIdx.x;
    const int lane = threadIdx.x;                 // 0..63

    const float* __restrict__ lrow = lp + (size_t)b * T_ * RS;

    const int lab   = y_true[b * L_ + lane];
    const int labm1 = __shfl_up(lab, 1, 64);
    const bool allow = (lane > 0) && (lab != labm1);

    float aE = NEGF, aO = NEGF, aL = NEGF;        // alpha[2i], alpha[2i+1], alpha[128]

    float4 va[NV], vb[NV];

    auto loadChunk = [&](int c, float4 (&v)[NV]) {
        const float4* g = (const float4*)(lrow + (size_t)c * CK * RS);
        #pragma unroll
        for (int k = 0; k < NV; ++k) v[k] = g[k * 64 + lane];   // coalesced 1KB/inst
    };
    auto writeChunk = [&](int sel, float4 (&v)[NV]) {
        float4* d = (float4*)&sbuf[sel][0];
        #pragma unroll
        for (int k = 0; k < NV; ++k) d[k * 64 + lane] = v[k];   // conflict-free b128
    };

    auto step = [&](float lpB, float lpL) {
        float upO = __shfl_up(aO, 1, 64);
        if (lane == 0) upO = NEGF;
        // s = 2i (blank): {2i, 2i-1}
        float mE = fmaxf(aE, upO);
        float nE = mE + __logf(__expf(aE - mE) + __expf(upO - mE)) + lpB;
        // s = 2i+1 (label): {2i+1, 2i, 2i-1 if allowed}
        float sk = allow ? upO : NEGF;
        float mO = fmaxf(fmaxf(aO, aE), sk);
        float nO = mO + __logf(__expf(aO - mO) + __expf(aE - mO) +
                               __expf(sk - mO)) + lpL;
        // s = 128 (blank, lane-63 local): {128, 127}
        float mL = fmaxf(aL, aO);
        float nL2 = mL + __logf(__expf(aL - mL) + __expf(aO - mL)) + lpB;
        aE = nE; aO = nO; aL = nL2;
    };

    auto scanChunk = [&](int sel, int rlo) {
        const float* B = &sbuf[sel][0];
        // 2-row ds_read ring ahead of the chain.
        float rB0 = B[rlo * RS],       rL0 = B[rlo * RS + 1 + lane];
        float rB1 = B[(rlo + 1) * RS], rL1 = B[(rlo + 1) * RS + 1 + lane];
        for (int j = rlo; j < CK; ++j) {
            float lpB = rB0, lpL = rL0;
            rB0 = rB1; rL0 = rL1;
            int nr = j + 2; if (nr > CK - 1) nr = CK - 1;       // clamped dup
            rB1 = B[nr * RS]; rL1 = B[nr * RS + 1 + lane];
            step(lpB, lpL);
        }
    };

    loadChunk(0, va); writeChunk(0, va);
    loadChunk(1, vb);                              // in flight during c0 scan

    // t = 0 init from LDS chunk 0, row 0.
    aE = (lane == 0) ? sbuf[0][0] : NEGF;
    aO = (lane == 0) ? sbuf[0][1] : NEGF;

    scanChunk(0, 1);                               // t = 1..63
    writeChunk(1, vb);
    loadChunk(2, va);                              // in flight during c1 scan
    scanChunk(1, 0);                               // t = 64..127
    writeChunk(0, va);
    loadChunk(3, vb);                              // in flight during c2 scan
    scanChunk(0, 0);                               // t = 128..191
    writeChunk(1, vb);
    scanChunk(1, 0);                               // t = 192..255

    if (lane == 63) {
        // loss = -logaddexp(alpha[128]=aL, alpha[127]=aO)
        float m = fmaxf(aL, aO);
        out[b] = -(m + __logf(__expf(aL - m) + __expf(aO - m)));
    }
}

extern "C" void kernel_launch(void* const* d_in, const int* in_sizes, int n_in,
                              void* d_out, int out_size, void* d_ws, size_t ws_size,
                              hipStream_t stream) {
    const int*   y_true = (const int*)d_in[0];
    const float* y_pred = (const float*)d_in[1];
    float*       out    = (float*)d_out;
    float*       lp     = (float*)d_ws;          // 256*256*68*4 = 17.8 MB
    (void)in_sizes; (void)n_in; (void)ws_size; (void)out_size;

    ctc_gather_kernel<<<dim3((256 * 256) / 4), dim3(256), 0, stream>>>(y_true, y_pred, lp);
    ctc_scan_kernel<<<dim3(256), dim3(64), 0, stream>>>(y_true, lp, out);
}